// Round 3
// baseline (151.840 us; speedup 1.0000x reference)
//
#include <hip/hip_runtime.h>
#include <hip/hip_bf16.h>
#include <stdint.h>
#include <stddef.h>

constexpr int Bc = 2;
constexpr int Sc = 4096;
constexpr int Dc = 512;
constexpr int Hc = 8;
constexpr int Wc = 32;

using bf16_t = __bf16;
typedef __attribute__((ext_vector_type(8))) __bf16 bf16x8;
typedef __attribute__((ext_vector_type(4))) __bf16 bf16x4;
typedef __attribute__((ext_vector_type(2))) __bf16 bf16x2;
typedef __attribute__((ext_vector_type(4))) float f32x4;

__device__ __forceinline__ void async_copy16(const void* g, void* l) {
    __builtin_amdgcn_global_load_lds(
        (const __attribute__((address_space(1))) void*)g,
        (__attribute__((address_space(3))) void*)l,
        16, 0, 0);
}

// All input conversions in one launch (inputs are fp32 — measured round 7).
// Blocks 0..4095: x (4 elem/thread). Blocks 4096..5119: the 4 weights.
__global__ void convert_all(const float* __restrict__ x,
                            const float* __restrict__ wq, const float* __restrict__ wk,
                            const float* __restrict__ wv, const float* __restrict__ wo,
                            bf16_t* __restrict__ xc, bf16_t* __restrict__ dq,
                            bf16_t* __restrict__ dk, bf16_t* __restrict__ dv,
                            bf16_t* __restrict__ dwo) {
    const int blk = blockIdx.x;
    const float* s; bf16_t* d; int base;
    if (blk < 4096) { s = x; d = xc; base = blk * 1024; }
    else {
        const int r = blk - 4096, which = r >> 8;
        s = (which == 0) ? wq : (which == 1) ? wk : (which == 2) ? wv : wo;
        d = (which == 0) ? dq : (which == 1) ? dk : (which == 2) ? dv : dwo;
        base = (r & 255) * 1024;
    }
    const int i = base + threadIdx.x * 4;
    const float4 v = *(const float4*)(s + i);
    bf16x4 o; o[0] = (bf16_t)v.x; o[1] = (bf16_t)v.y;
    o[2] = (bf16_t)v.z; o[3] = (bf16_t)v.w;
    *(bf16x4*)(d + i) = o;
}

// C = A @ B^T (verified rounds 3-9). nPerB>0: virtual B=[B0;B1;B2].
// Round 11: bijective XCD swizzle on the linearized block id (T1).
template<int BM, int BN, int TM, int TN, bool F32OUT>
__global__ __launch_bounds__(256) void gemm_bt(
    const bf16_t* __restrict__ A, int lda,
    const bf16_t* __restrict__ B0, const bf16_t* __restrict__ B1,
    const bf16_t* __restrict__ B2, int ldb, int nPerB,
    void* __restrict__ C, int ldc, int K)
{
    constexpr int BK = 32;
    __shared__ __align__(1024) bf16_t Alds[BM * BK];
    __shared__ __align__(1024) bf16_t Blds[BN * BK];

    const int tid  = threadIdx.x;
    const int lane = tid & 63;
    const int wv   = tid >> 6;
    const int wm   = wv >> 1;
    const int wn   = wv & 1;
    const int r    = lane & 15;
    const int q4   = lane >> 4;

    // XCD-aware remap: blocks resident on one XCD cover contiguous tile ids.
    const int nwgx = gridDim.x;
    const int nwg  = nwgx * gridDim.y;          // always a multiple of 8 here
    int id = blockIdx.y * nwgx + blockIdx.x;
    id = (id & 7) * (nwg >> 3) + (id >> 3);
    const int byi = id / nwgx;
    const int bxi = id - byi * nwgx;

    const int blkM = bxi * BM;
    const int colC = byi * BN;

    const bf16_t* Bp = B0;
    int nB = colC;
    if (nPerB > 0) {
        int wsel = colC / nPerB;
        nB = colC - wsel * nPerB;
        Bp = (wsel == 0) ? B0 : (wsel == 1) ? B1 : B2;
    }

    f32x4 acc[TM][TN];
    const f32x4 fzero = {0.f, 0.f, 0.f, 0.f};
    #pragma unroll
    for (int i = 0; i < TM; ++i)
        #pragma unroll
        for (int j = 0; j < TN; ++j) acc[i][j] = fzero;

    constexpr int A_LOADS = (BM * BK * 2) / (256 * 16);
    constexpr int B_LOADS = (BN * BK * 2) / (256 * 16);

    for (int kk = 0; kk < K; kk += BK) {
        __syncthreads();
        #pragma unroll
        for (int i = 0; i < A_LOADS; ++i) {
            int off  = i * 4096 + tid * 16;
            int row  = off >> 6;
            int colb = off & 63;
            const char* g = (const char*)A + ((size_t)(blkM + row) * lda + kk) * 2 + colb;
            async_copy16(g, (char*)Alds + off);
        }
        #pragma unroll
        for (int i = 0; i < B_LOADS; ++i) {
            int off  = i * 4096 + tid * 16;
            int row  = off >> 6;
            int colb = off & 63;
            const char* g = (const char*)Bp + ((size_t)(nB + row) * ldb + kk) * 2 + colb;
            async_copy16(g, (char*)Blds + off);
        }
        __syncthreads();

        bf16x8 af[TM], bfr[TN];
        #pragma unroll
        for (int mt = 0; mt < TM; ++mt)
            af[mt] = *(const bf16x8*)&Alds[(wm * TM * 16 + mt * 16 + r) * BK + q4 * 8];
        #pragma unroll
        for (int nt = 0; nt < TN; ++nt)
            bfr[nt] = *(const bf16x8*)&Blds[(wn * TN * 16 + nt * 16 + r) * BK + q4 * 8];

        #pragma unroll
        for (int mt = 0; mt < TM; ++mt)
            #pragma unroll
            for (int nt = 0; nt < TN; ++nt)
                acc[mt][nt] = __builtin_amdgcn_mfma_f32_16x16x32_bf16(
                    af[mt], bfr[nt], acc[mt][nt], 0, 0, 0);
    }

    #pragma unroll
    for (int mt = 0; mt < TM; ++mt) {
        #pragma unroll
        for (int nt = 0; nt < TN; ++nt) {
            int rr0 = blkM + wm * TM * 16 + mt * 16 + q4 * 4;
            int cc  = colC + wn * TN * 16 + nt * 16 + r;
            #pragma unroll
            for (int i = 0; i < 4; ++i) {
                size_t o = (size_t)(rr0 + i) * ldc + cc;
                if constexpr (F32OUT) ((float*)C)[o]  = acc[mt][nt][i];
                else                  ((bf16_t*)C)[o] = (bf16_t)acc[mt][nt][i];
            }
        }
    }
}

// Neighbor attention — register-only (round 10) + 8-consecutive-s blocks
// (round 11) for L1 gather reuse: Hilbert-adjacent queries share most of
// their 32-neighbor K/V rows; a block's combined gather working set
// (~15 KB) fits L1, halving L2/L3 gather traffic vs 4-s blocks.
// Lane map: wq = lane>>3 (neighbor subgroup), d8 = lane&7 (dim octet).
__global__ __launch_bounds__(256) void attn_fast(
    const bf16_t* __restrict__ QKV,
    const int*    __restrict__ nidx,
    bf16_t*       __restrict__ attn_out)
{
    const int lane = threadIdx.x & 63;
    const int wv   = threadIdx.x >> 6;

    // XCD swizzle: contiguous item-range per XCD (per-XCD working set ~3 MB).
    const int bi  = blockIdx.x;                    // 8192 blocks
    const int blk = (bi & 7) * 1024 + (bi >> 3);
    const int item0 = blk * 8 + wv * 2;            // ((b*8+h)<<12) + s, s even
    const int h = (item0 >> 12) & (Hc - 1);
    const int b = item0 >> 15;
    const int s0 = item0 & (Sc - 1);

    const int d8 = lane & 7;                       // dims 8*d8 .. 8*d8+7
    const int wq = lane >> 3;                      // neighbors g*8 + wq

    const char* qkvB  = (const char*)QKV;
    const char* Kbase = qkvB + (size_t)b * Sc * 3072 + 1024 + h * 128 + d8 * 16;
    const char* Vbase = qkvB + (size_t)b * Sc * 3072 + 2048 + h * 128 + d8 * 16;

    #pragma unroll
    for (int ss = 0; ss < 2; ++ss) {
        const int s = s0 + ss;
        const size_t row = (size_t)b * Sc + s;
        const bf16x8 q8 = *(const bf16x8*)(qkvB + row * 3072 + h * 128 + d8 * 16);

        // Phase 1: 4 neighbors per lane-subgroup; K and V issued together.
        float  p[4];
        bf16x8 v8s[4];
        #pragma unroll
        for (int g = 0; g < 4; ++g) {
            const int t = nidx[s * Wc + g * 8 + wq];
            const size_t toff = (size_t)t * 3072;
            const bf16x8 k8 = *(const bf16x8*)(Kbase + toff);
            v8s[g] = *(const bf16x8*)(Vbase + toff);
            float d = 0.f;
            #pragma unroll
            for (int j = 0; j < 8; ++j) d += (float)q8[j] * (float)k8[j];
            d += __shfl_xor(d, 1);
            d += __shfl_xor(d, 2);
            d += __shfl_xor(d, 4);
            p[g] = d * 0.125f;                     // 1/sqrt(64)
        }

        // Softmax over 32 neighbors: local over g, butterfly over wq.
        float mx = fmaxf(fmaxf(p[0], p[1]), fmaxf(p[2], p[3]));
        mx = fmaxf(mx, __shfl_xor(mx, 8));
        mx = fmaxf(mx, __shfl_xor(mx, 16));
        mx = fmaxf(mx, __shfl_xor(mx, 32));
        float e[4];
        float sum = 0.f;
        #pragma unroll
        for (int g = 0; g < 4; ++g) { e[g] = __expf(p[g] - mx); sum += e[g]; }
        sum += __shfl_xor(sum, 8);
        sum += __shfl_xor(sum, 16);
        sum += __shfl_xor(sum, 32);
        const float inv = 1.0f / sum;

        // Phase 2: PV with weights in-register in the consuming lanes.
        float acc[8] = {0.f, 0.f, 0.f, 0.f, 0.f, 0.f, 0.f, 0.f};
        #pragma unroll
        for (int g = 0; g < 4; ++g) {
            const float ag = e[g] * inv;
            #pragma unroll
            for (int j = 0; j < 8; ++j)
                acc[j] = fmaf(ag, (float)v8s[g][j], acc[j]);
        }
        #pragma unroll
        for (int j = 0; j < 8; ++j) {
            acc[j] += __shfl_xor(acc[j], 8);
            acc[j] += __shfl_xor(acc[j], 16);
            acc[j] += __shfl_xor(acc[j], 32);
        }
        if (wq == 0) {
            bf16x8 o;
            #pragma unroll
            for (int j = 0; j < 8; ++j) o[j] = (bf16_t)acc[j];
            *(bf16x8*)((char*)attn_out + row * 1024 + h * 128 + d8 * 16) = o;
        }
    }
}

extern "C" void kernel_launch(void* const* d_in, const int* in_sizes, int n_in,
                              void* d_out, int out_size, void* d_ws, size_t ws_size,
                              hipStream_t stream) {
    (void)in_sizes; (void)n_in; (void)out_size; (void)ws_size;
    const int* nidx = (const int*)d_in[5];
    const int M = Bc * Sc;                        // 8192
    float* out = (float*)d_out;                   // fp32 output (round-7 finding)

    char* w = (char*)d_ws;
    bf16_t* xc   = (bf16_t*)(w + 256);            // 8 MB
    bf16_t* Wqc  = xc  + 4194304;                 // 0.5 MB each
    bf16_t* Wkc  = Wqc + 262144;
    bf16_t* Wvc  = Wkc + 262144;
    bf16_t* Woc  = Wvc + 262144;
    bf16_t* qkv  = Woc + 262144;                  // 24 MB
    bf16_t* attnS = xc;                           // reuse x-buffer after GEMM1

    convert_all<<<5120, 256, 0, stream>>>(
        (const float*)d_in[0], (const float*)d_in[1], (const float*)d_in[2],
        (const float*)d_in[3], (const float*)d_in[4],
        xc, Wqc, Wkc, Wvc, Woc);

    // Fused QKV projection: M=8192, N=1536, K=512 (bf16 out).
    gemm_bt<128, 128, 4, 4, false><<<dim3(M / 128, 1536 / 128), 256, 0, stream>>>(
        xc, Dc, Wqc, Wkc, Wvc, Dc, 512, qkv, 1536, Dc);

    // Neighbor attention: 8 consecutive s per block (L1 gather reuse).
    attn_fast<<<(Bc * Hc * Sc) / 8, 256, 0, stream>>>(qkv, nidx, attnS);

    // Output projection: M=8192, N=512, K=512 -> fp32 d_out.
    gemm_bt<128, 128, 4, 4, true><<<dim3(M / 128, 512 / 128), 256, 0, stream>>>(
        attnS, 512, Woc, Woc, Woc, 512, 0, out, Dc, Dc);
}

// Round 4
// 144.183 us; speedup vs baseline: 1.0531x; 1.0531x over previous
//
#include <hip/hip_runtime.h>
#include <hip/hip_bf16.h>
#include <stdint.h>
#include <stddef.h>

constexpr int Bc = 2;
constexpr int Sc = 4096;
constexpr int Dc = 512;
constexpr int Hc = 8;
constexpr int Wc = 32;

using bf16_t = __bf16;
typedef __attribute__((ext_vector_type(8))) __bf16 bf16x8;
typedef __attribute__((ext_vector_type(4))) __bf16 bf16x4;
typedef __attribute__((ext_vector_type(2))) __bf16 bf16x2;
typedef __attribute__((ext_vector_type(4))) float f32x4;

__device__ __forceinline__ void async_copy16(const void* g, void* l) {
    __builtin_amdgcn_global_load_lds(
        (const __attribute__((address_space(1))) void*)g,
        (__attribute__((address_space(3))) void*)l,
        16, 0, 0);
}

// All input conversions in one launch (inputs are fp32 — measured round 7).
// Blocks 0..4095: x (4 elem/thread). Blocks 4096..5119: the 4 weights.
__global__ void convert_all(const float* __restrict__ x,
                            const float* __restrict__ wq, const float* __restrict__ wk,
                            const float* __restrict__ wv, const float* __restrict__ wo,
                            bf16_t* __restrict__ xc, bf16_t* __restrict__ dq,
                            bf16_t* __restrict__ dk, bf16_t* __restrict__ dv,
                            bf16_t* __restrict__ dwo) {
    const int blk = blockIdx.x;
    const float* s; bf16_t* d; int base;
    if (blk < 4096) { s = x; d = xc; base = blk * 1024; }
    else {
        const int r = blk - 4096, which = r >> 8;
        s = (which == 0) ? wq : (which == 1) ? wk : (which == 2) ? wv : wo;
        d = (which == 0) ? dq : (which == 1) ? dk : (which == 2) ? dv : dwo;
        base = (r & 255) * 1024;
    }
    const int i = base + threadIdx.x * 4;
    const float4 v = *(const float4*)(s + i);
    bf16x4 o; o[0] = (bf16_t)v.x; o[1] = (bf16_t)v.y;
    o[2] = (bf16_t)v.z; o[3] = (bf16_t)v.w;
    *(bf16x4*)(d + i) = o;
}

// C = A @ B^T (verified rounds 3-9). nPerB>0: virtual B=[B0;B1;B2].
template<int BM, int BN, int TM, int TN, bool F32OUT>
__global__ __launch_bounds__(256) void gemm_bt(
    const bf16_t* __restrict__ A, int lda,
    const bf16_t* __restrict__ B0, const bf16_t* __restrict__ B1,
    const bf16_t* __restrict__ B2, int ldb, int nPerB,
    void* __restrict__ C, int ldc, int K)
{
    constexpr int BK = 32;
    __shared__ __align__(1024) bf16_t Alds[BM * BK];
    __shared__ __align__(1024) bf16_t Blds[BN * BK];

    const int tid  = threadIdx.x;
    const int lane = tid & 63;
    const int wv   = tid >> 6;
    const int wm   = wv >> 1;
    const int wn   = wv & 1;
    const int r    = lane & 15;
    const int q4   = lane >> 4;

    const int blkM = blockIdx.x * BM;
    const int colC = blockIdx.y * BN;

    const bf16_t* Bp = B0;
    int nB = colC;
    if (nPerB > 0) {
        int wsel = colC / nPerB;
        nB = colC - wsel * nPerB;
        Bp = (wsel == 0) ? B0 : (wsel == 1) ? B1 : B2;
    }

    f32x4 acc[TM][TN];
    const f32x4 fzero = {0.f, 0.f, 0.f, 0.f};
    #pragma unroll
    for (int i = 0; i < TM; ++i)
        #pragma unroll
        for (int j = 0; j < TN; ++j) acc[i][j] = fzero;

    constexpr int A_LOADS = (BM * BK * 2) / (256 * 16);
    constexpr int B_LOADS = (BN * BK * 2) / (256 * 16);

    for (int kk = 0; kk < K; kk += BK) {
        __syncthreads();
        #pragma unroll
        for (int i = 0; i < A_LOADS; ++i) {
            int off  = i * 4096 + tid * 16;
            int row  = off >> 6;
            int colb = off & 63;
            const char* g = (const char*)A + ((size_t)(blkM + row) * lda + kk) * 2 + colb;
            async_copy16(g, (char*)Alds + off);
        }
        #pragma unroll
        for (int i = 0; i < B_LOADS; ++i) {
            int off  = i * 4096 + tid * 16;
            int row  = off >> 6;
            int colb = off & 63;
            const char* g = (const char*)Bp + ((size_t)(nB + row) * ldb + kk) * 2 + colb;
            async_copy16(g, (char*)Blds + off);
        }
        __syncthreads();

        bf16x8 af[TM], bfr[TN];
        #pragma unroll
        for (int mt = 0; mt < TM; ++mt)
            af[mt] = *(const bf16x8*)&Alds[(wm * TM * 16 + mt * 16 + r) * BK + q4 * 8];
        #pragma unroll
        for (int nt = 0; nt < TN; ++nt)
            bfr[nt] = *(const bf16x8*)&Blds[(wn * TN * 16 + nt * 16 + r) * BK + q4 * 8];

        #pragma unroll
        for (int mt = 0; mt < TM; ++mt)
            #pragma unroll
            for (int nt = 0; nt < TN; ++nt)
                acc[mt][nt] = __builtin_amdgcn_mfma_f32_16x16x32_bf16(
                    af[mt], bfr[nt], acc[mt][nt], 0, 0, 0);
    }

    #pragma unroll
    for (int mt = 0; mt < TM; ++mt) {
        #pragma unroll
        for (int nt = 0; nt < TN; ++nt) {
            int rr0 = blkM + wm * TM * 16 + mt * 16 + q4 * 4;
            int cc  = colC + wn * TN * 16 + nt * 16 + r;
            #pragma unroll
            for (int i = 0; i < 4; ++i) {
                size_t o = (size_t)(rr0 + i) * ldc + cc;
                if constexpr (F32OUT) ((float*)C)[o]  = acc[mt][nt][i];
                else                  ((bf16_t*)C)[o] = (bf16_t)acc[mt][nt][i];
            }
        }
    }
}

// Neighbor attention, one wave per (b,h,s) — register-only (round-10 form).
// Lane map: wq = lane>>3 (neighbor subgroup), d8 = lane&7 (dim octet).
// Per lane: 1x16B Q, 4x16B K, 4x16B V loads. Softmax weights stay in the
// lanes that consume them in PV: no LDS, no __syncthreads.
__global__ __launch_bounds__(256) void attn_fast(
    const bf16_t* __restrict__ QKV,
    const int*    __restrict__ nidx,
    bf16_t*       __restrict__ attn_out)
{
    const int lane = threadIdx.x & 63;
    const int wv   = threadIdx.x >> 6;

    // XCD swizzle: contiguous s-range per XCD for gather L2 locality.
    const int bi  = blockIdx.x;
    const int blk = (bi & 7) * 2048 + (bi >> 3);
    const int wg  = blk * 4 + wv;                  // ((b*8+h)<<12) + s
    const int s = wg & (Sc - 1);
    const int h = (wg >> 12) & (Hc - 1);
    const int b = wg >> 15;
    const size_t row = (size_t)b * Sc + s;

    const int d8 = lane & 7;                       // dims 8*d8 .. 8*d8+7
    const int wq = lane >> 3;                      // neighbors g*8 + wq

    const char* qkvB  = (const char*)QKV;
    const bf16x8 q8   = *(const bf16x8*)(qkvB + row * 3072 + h * 128 + d8 * 16);
    const char* Kbase = qkvB + (size_t)b * Sc * 3072 + 1024 + h * 128 + d8 * 16;
    const char* Vbase = qkvB + (size_t)b * Sc * 3072 + 2048 + h * 128 + d8 * 16;

    // Phase 1: 4 neighbors per lane-subgroup; K and V issued together so V's
    // latency hides under the dot/softmax.
    float  p[4];
    bf16x8 v8s[4];
    #pragma unroll
    for (int g = 0; g < 4; ++g) {
        const int t = nidx[s * Wc + g * 8 + wq];
        const size_t toff = (size_t)t * 3072;
        const bf16x8 k8 = *(const bf16x8*)(Kbase + toff);
        v8s[g] = *(const bf16x8*)(Vbase + toff);
        float d = 0.f;
        #pragma unroll
        for (int j = 0; j < 8; ++j) d += (float)q8[j] * (float)k8[j];
        d += __shfl_xor(d, 1);
        d += __shfl_xor(d, 2);
        d += __shfl_xor(d, 4);
        p[g] = d * 0.125f;                         // 1/sqrt(64)
    }

    // Softmax over all 32 neighbors: local max/sum over g, butterfly over wq.
    float mx = fmaxf(fmaxf(p[0], p[1]), fmaxf(p[2], p[3]));
    mx = fmaxf(mx, __shfl_xor(mx, 8));
    mx = fmaxf(mx, __shfl_xor(mx, 16));
    mx = fmaxf(mx, __shfl_xor(mx, 32));
    float e[4];
    float sum = 0.f;
    #pragma unroll
    for (int g = 0; g < 4; ++g) { e[g] = __expf(p[g] - mx); sum += e[g]; }
    sum += __shfl_xor(sum, 8);
    sum += __shfl_xor(sum, 16);
    sum += __shfl_xor(sum, 32);
    const float inv = 1.0f / sum;

    // Phase 2: PV with weights already in-register in the right lanes.
    float acc[8] = {0.f, 0.f, 0.f, 0.f, 0.f, 0.f, 0.f, 0.f};
    #pragma unroll
    for (int g = 0; g < 4; ++g) {
        const float ag = e[g] * inv;
        #pragma unroll
        for (int j = 0; j < 8; ++j)
            acc[j] = fmaf(ag, (float)v8s[g][j], acc[j]);
    }
    // Reduce over the 8 neighbor-subgroups.
    #pragma unroll
    for (int j = 0; j < 8; ++j) {
        acc[j] += __shfl_xor(acc[j], 8);
        acc[j] += __shfl_xor(acc[j], 16);
        acc[j] += __shfl_xor(acc[j], 32);
    }
    if (wq == 0) {
        bf16x8 o;
        #pragma unroll
        for (int j = 0; j < 8; ++j) o[j] = (bf16_t)acc[j];
        *(bf16x8*)((char*)attn_out + row * 1024 + h * 128 + d8 * 16) = o;
    }
}

extern "C" void kernel_launch(void* const* d_in, const int* in_sizes, int n_in,
                              void* d_out, int out_size, void* d_ws, size_t ws_size,
                              hipStream_t stream) {
    (void)in_sizes; (void)n_in; (void)out_size; (void)ws_size;
    const int* nidx = (const int*)d_in[5];
    const int M = Bc * Sc;                        // 8192
    float* out = (float*)d_out;                   // fp32 output (round-7 finding)

    char* w = (char*)d_ws;
    bf16_t* xc   = (bf16_t*)(w + 256);            // 8 MB
    bf16_t* Wqc  = xc  + 4194304;                 // 0.5 MB each
    bf16_t* Wkc  = Wqc + 262144;
    bf16_t* Wvc  = Wkc + 262144;
    bf16_t* Woc  = Wvc + 262144;
    bf16_t* qkv  = Woc + 262144;                  // 24 MB
    bf16_t* attnS = xc;                           // reuse x-buffer after GEMM1

    convert_all<<<5120, 256, 0, stream>>>(
        (const float*)d_in[0], (const float*)d_in[1], (const float*)d_in[2],
        (const float*)d_in[3], (const float*)d_in[4],
        xc, Wqc, Wkc, Wvc, Woc);

    // Fused QKV projection: M=8192, N=1536, K=512 (bf16 out).
    gemm_bt<128, 128, 4, 4, false><<<dim3(M / 128, 1536 / 128), 256, 0, stream>>>(
        xc, Dc, Wqc, Wkc, Wvc, Dc, 512, qkv, 1536, Dc);

    // Neighbor attention (register-only, 1 query/wave, max TLP).
    attn_fast<<<(Bc * Hc * Sc) / 4, 256, 0, stream>>>(qkv, nidx, attnS);

    // Output projection: M=8192, N=512, K=512 -> fp32 d_out.
    // 512 blocks (2 blocks/CU co-residency — round-0 measured config).
    gemm_bt<128, 64, 4, 2, true><<<dim3(M / 128, 512 / 64), 256, 0, stream>>>(
        attnS, 512, Woc, Woc, Woc, 512, 0, out, Dc, Dc);
}

// Round 5
// 142.438 us; speedup vs baseline: 1.0660x; 1.0123x over previous
//
#include <hip/hip_runtime.h>
#include <hip/hip_bf16.h>
#include <stdint.h>
#include <stddef.h>

constexpr int Bc = 2;
constexpr int Sc = 4096;
constexpr int Dc = 512;
constexpr int Hc = 8;
constexpr int Wc = 32;

using bf16_t = __bf16;
typedef __attribute__((ext_vector_type(8))) __bf16 bf16x8;
typedef __attribute__((ext_vector_type(4))) __bf16 bf16x4;
typedef __attribute__((ext_vector_type(2))) __bf16 bf16x2;
typedef __attribute__((ext_vector_type(4))) float f32x4;

__device__ __forceinline__ void async_copy16(const void* g, void* l) {
    __builtin_amdgcn_global_load_lds(
        (const __attribute__((address_space(1))) void*)g,
        (__attribute__((address_space(3))) void*)l,
        16, 0, 0);
}

// All input conversions in one launch (inputs are fp32 — measured round 7).
__global__ void convert_all(const float* __restrict__ x,
                            const float* __restrict__ wq, const float* __restrict__ wk,
                            const float* __restrict__ wv, const float* __restrict__ wo,
                            bf16_t* __restrict__ xc, bf16_t* __restrict__ dq,
                            bf16_t* __restrict__ dk, bf16_t* __restrict__ dv,
                            bf16_t* __restrict__ dwo) {
    const int blk = blockIdx.x;
    const float* s; bf16_t* d; int base;
    if (blk < 4096) { s = x; d = xc; base = blk * 1024; }
    else {
        const int r = blk - 4096, which = r >> 8;
        s = (which == 0) ? wq : (which == 1) ? wk : (which == 2) ? wv : wo;
        d = (which == 0) ? dq : (which == 1) ? dk : (which == 2) ? dv : dwo;
        base = (r & 255) * 1024;
    }
    const int i = base + threadIdx.x * 4;
    const float4 v = *(const float4*)(s + i);
    bf16x4 o; o[0] = (bf16_t)v.x; o[1] = (bf16_t)v.y;
    o[2] = (bf16_t)v.z; o[3] = (bf16_t)v.w;
    *(bf16x4*)(d + i) = o;
}

// ---------------------------------------------------------------------------
// GEMM1 (QKV): 256x256 tile, BK=64 (two 32-wide halves), 8 waves (2M x 4N),
// 16 half-phases with counted vmcnt(8) (T3+T4) + setprio (T5).
// C = A @ [B0;B1;B2]^T, M=8192 N=1536 K=512, bf16 out, ldc=1536.
// Fragment math identical to the verified gemm_bt (64B LDS rows, r/q4 map).
// Pipeline: prefetch depth 3 half-tiles; each phase stages half p+3 (4 x
// global_load_lds), reads 12 frags, 32 MFMA, then vmcnt(8)+barrier drains
// exactly half p+1 in every wave -> cross-wave complete after the barrier.
// ---------------------------------------------------------------------------
__global__ __launch_bounds__(512, 2) void gemm8p(
    const bf16_t* __restrict__ A,
    const bf16_t* __restrict__ B0, const bf16_t* __restrict__ B1,
    const bf16_t* __restrict__ B2,
    bf16_t* __restrict__ C)
{
    __shared__ __align__(1024) char lds[131072];   // A:[0,64K) B:[64K,128K)
    char* ldsA = lds;
    char* ldsB = lds + 65536;

    const int tid  = threadIdx.x;
    const int lane = tid & 63;
    const int wv_  = tid >> 6;
    const int wm   = wv_ >> 2;      // M-half   0..1  (rows wm*128..+128)
    const int wn   = wv_ & 3;       // N-quarter 0..3 (cols wn*64..+64)
    const int r    = lane & 15;
    const int q4   = lane >> 4;

    // Bijective XCD swizzle over 192 blocks (192 % 8 == 0).
    int id = blockIdx.y * gridDim.x + blockIdx.x;
    id = (id & 7) * 24 + (id >> 3);
    const int bxi = id & 31;
    const int byi = id >> 5;
    const int blkM = bxi * 256;
    const int colC = byi * 256;

    const int wsel = colC >> 9;              // virtual B = [Wq;Wk;Wv]
    const int nB   = colC & 511;             // BN=256 never straddles (512%256==0)
    const bf16_t* Bp = (wsel == 0) ? B0 : (wsel == 1) ? B1 : B2;

    f32x4 acc[8][4];
    const f32x4 fzero = {0.f, 0.f, 0.f, 0.f};
    #pragma unroll
    for (int i = 0; i < 8; ++i)
        #pragma unroll
        for (int j = 0; j < 4; ++j) acc[i][j] = fzero;

    // Stage half h (h = T*2+ks): A rows [blkM,+256) x k [h*32,+32) and same for B.
    auto stage = [&](int h) {
        const int kcol = h * 32;
        char* dA = ldsA + ((h >> 1) & 1) * 32768 + (h & 1) * 16384;
        char* dB = ldsB + ((h >> 1) & 1) * 32768 + (h & 1) * 16384;
        #pragma unroll
        for (int i = 0; i < 2; ++i) {
            const int o = i * 8192 + tid * 16;
            const int row = o >> 6, colb = o & 63;
            async_copy16((const char*)A + ((size_t)(blkM + row) * 512 + kcol) * 2 + colb,
                         dA + o);
        }
        #pragma unroll
        for (int i = 0; i < 2; ++i) {
            const int o = i * 8192 + tid * 16;
            const int row = o >> 6, colb = o & 63;
            async_copy16((const char*)Bp + ((size_t)(nB + row) * 512 + kcol) * 2 + colb,
                         dB + o);
        }
    };

    // Compute half-phase p: 12 ds_read_b128 + 32 MFMA (K=32 slice).
    auto phase = [&](int p) {
        const char* aB = ldsA + ((p >> 1) & 1) * 32768 + (p & 1) * 16384;
        const char* bB = ldsB + ((p >> 1) & 1) * 32768 + (p & 1) * 16384;
        bf16x8 af[8], bfr[4];
        #pragma unroll
        for (int mt = 0; mt < 8; ++mt)
            af[mt] = *(const bf16x8*)(aB + (wm * 128 + mt * 16 + r) * 64 + q4 * 16);
        #pragma unroll
        for (int nt = 0; nt < 4; ++nt)
            bfr[nt] = *(const bf16x8*)(bB + (wn * 64 + nt * 16 + r) * 64 + q4 * 16);
        __builtin_amdgcn_s_setprio(1);
        #pragma unroll
        for (int mt = 0; mt < 8; ++mt)
            #pragma unroll
            for (int nt = 0; nt < 4; ++nt)
                acc[mt][nt] = __builtin_amdgcn_mfma_f32_16x16x32_bf16(
                    af[mt], bfr[nt], acc[mt][nt], 0, 0, 0);
        __builtin_amdgcn_s_setprio(0);
    };

    // Prologue: 3 half-tiles in flight; drain half 0.
    stage(0); stage(1); stage(2);
    asm volatile("s_waitcnt vmcnt(8)" ::: "memory");
    __builtin_amdgcn_s_barrier();

    // Steady state: 13 phases with stage(p+3) and vmcnt(8) (never 0).
    for (int p = 0; p < 13; ++p) {
        stage(p + 3);
        phase(p);
        asm volatile("s_waitcnt vmcnt(8)" ::: "memory");
        __builtin_amdgcn_s_barrier();
    }
    // Tail drain: 13 -> vmcnt(4), 14 -> vmcnt(0), 15 -> compute only.
    phase(13);
    asm volatile("s_waitcnt vmcnt(4)" ::: "memory");
    __builtin_amdgcn_s_barrier();
    phase(14);
    asm volatile("s_waitcnt vmcnt(0)" ::: "memory");
    __builtin_amdgcn_s_barrier();
    phase(15);

    // Epilogue: bf16 C, ldc = 1536.
    #pragma unroll
    for (int mt = 0; mt < 8; ++mt)
        #pragma unroll
        for (int nt = 0; nt < 4; ++nt) {
            const int rr0 = blkM + wm * 128 + mt * 16 + q4 * 4;
            const int cc  = colC + wn * 64 + nt * 16 + r;
            #pragma unroll
            for (int i = 0; i < 4; ++i)
                C[(size_t)(rr0 + i) * 1536 + cc] = (bf16_t)acc[mt][nt][i];
        }
}

// C = A @ B^T (verified rounds 3-9) — kept for the output projection.
template<int BM, int BN, int TM, int TN, bool F32OUT>
__global__ __launch_bounds__(256) void gemm_bt(
    const bf16_t* __restrict__ A, int lda,
    const bf16_t* __restrict__ B0, const bf16_t* __restrict__ B1,
    const bf16_t* __restrict__ B2, int ldb, int nPerB,
    void* __restrict__ C, int ldc, int K)
{
    constexpr int BK = 32;
    __shared__ __align__(1024) bf16_t Alds[BM * BK];
    __shared__ __align__(1024) bf16_t Blds[BN * BK];

    const int tid  = threadIdx.x;
    const int lane = tid & 63;
    const int wv   = tid >> 6;
    const int wm   = wv >> 1;
    const int wn   = wv & 1;
    const int r    = lane & 15;
    const int q4   = lane >> 4;

    const int blkM = blockIdx.x * BM;
    const int colC = blockIdx.y * BN;

    const bf16_t* Bp = B0;
    int nB = colC;
    if (nPerB > 0) {
        int wsel = colC / nPerB;
        nB = colC - wsel * nPerB;
        Bp = (wsel == 0) ? B0 : (wsel == 1) ? B1 : B2;
    }

    f32x4 acc[TM][TN];
    const f32x4 fzero = {0.f, 0.f, 0.f, 0.f};
    #pragma unroll
    for (int i = 0; i < TM; ++i)
        #pragma unroll
        for (int j = 0; j < TN; ++j) acc[i][j] = fzero;

    constexpr int A_LOADS = (BM * BK * 2) / (256 * 16);
    constexpr int B_LOADS = (BN * BK * 2) / (256 * 16);

    for (int kk = 0; kk < K; kk += BK) {
        __syncthreads();
        #pragma unroll
        for (int i = 0; i < A_LOADS; ++i) {
            int off  = i * 4096 + tid * 16;
            int row  = off >> 6;
            int colb = off & 63;
            const char* g = (const char*)A + ((size_t)(blkM + row) * lda + kk) * 2 + colb;
            async_copy16(g, (char*)Alds + off);
        }
        #pragma unroll
        for (int i = 0; i < B_LOADS; ++i) {
            int off  = i * 4096 + tid * 16;
            int row  = off >> 6;
            int colb = off & 63;
            const char* g = (const char*)Bp + ((size_t)(nB + row) * ldb + kk) * 2 + colb;
            async_copy16(g, (char*)Blds + off);
        }
        __syncthreads();

        bf16x8 af[TM], bfr[TN];
        #pragma unroll
        for (int mt = 0; mt < TM; ++mt)
            af[mt] = *(const bf16x8*)&Alds[(wm * TM * 16 + mt * 16 + r) * BK + q4 * 8];
        #pragma unroll
        for (int nt = 0; nt < TN; ++nt)
            bfr[nt] = *(const bf16x8*)&Blds[(wn * TN * 16 + nt * 16 + r) * BK + q4 * 8];

        #pragma unroll
        for (int mt = 0; mt < TM; ++mt)
            #pragma unroll
            for (int nt = 0; nt < TN; ++nt)
                acc[mt][nt] = __builtin_amdgcn_mfma_f32_16x16x32_bf16(
                    af[mt], bfr[nt], acc[mt][nt], 0, 0, 0);
    }

    #pragma unroll
    for (int mt = 0; mt < TM; ++mt) {
        #pragma unroll
        for (int nt = 0; nt < TN; ++nt) {
            int rr0 = blkM + wm * TM * 16 + mt * 16 + q4 * 4;
            int cc  = colC + wn * TN * 16 + nt * 16 + r;
            #pragma unroll
            for (int i = 0; i < 4; ++i) {
                size_t o = (size_t)(rr0 + i) * ldc + cc;
                if constexpr (F32OUT) ((float*)C)[o]  = acc[mt][nt][i];
                else                  ((bf16_t*)C)[o] = (bf16_t)acc[mt][nt][i];
            }
        }
    }
}

// Neighbor attention, one wave per (b,h,s) — register-only (round-10 form).
__global__ __launch_bounds__(256) void attn_fast(
    const bf16_t* __restrict__ QKV,
    const int*    __restrict__ nidx,
    bf16_t*       __restrict__ attn_out)
{
    const int lane = threadIdx.x & 63;
    const int wv   = threadIdx.x >> 6;

    const int bi  = blockIdx.x;
    const int blk = (bi & 7) * 2048 + (bi >> 3);
    const int wg  = blk * 4 + wv;                  // ((b*8+h)<<12) + s
    const int s = wg & (Sc - 1);
    const int h = (wg >> 12) & (Hc - 1);
    const int b = wg >> 15;
    const size_t row = (size_t)b * Sc + s;

    const int d8 = lane & 7;
    const int wq = lane >> 3;

    const char* qkvB  = (const char*)QKV;
    const bf16x8 q8   = *(const bf16x8*)(qkvB + row * 3072 + h * 128 + d8 * 16);
    const char* Kbase = qkvB + (size_t)b * Sc * 3072 + 1024 + h * 128 + d8 * 16;
    const char* Vbase = qkvB + (size_t)b * Sc * 3072 + 2048 + h * 128 + d8 * 16;

    float  p[4];
    bf16x8 v8s[4];
    #pragma unroll
    for (int g = 0; g < 4; ++g) {
        const int t = nidx[s * Wc + g * 8 + wq];
        const size_t toff = (size_t)t * 3072;
        const bf16x8 k8 = *(const bf16x8*)(Kbase + toff);
        v8s[g] = *(const bf16x8*)(Vbase + toff);
        float d = 0.f;
        #pragma unroll
        for (int j = 0; j < 8; ++j) d += (float)q8[j] * (float)k8[j];
        d += __shfl_xor(d, 1);
        d += __shfl_xor(d, 2);
        d += __shfl_xor(d, 4);
        p[g] = d * 0.125f;
    }

    float mx = fmaxf(fmaxf(p[0], p[1]), fmaxf(p[2], p[3]));
    mx = fmaxf(mx, __shfl_xor(mx, 8));
    mx = fmaxf(mx, __shfl_xor(mx, 16));
    mx = fmaxf(mx, __shfl_xor(mx, 32));
    float e[4];
    float sum = 0.f;
    #pragma unroll
    for (int g = 0; g < 4; ++g) { e[g] = __expf(p[g] - mx); sum += e[g]; }
    sum += __shfl_xor(sum, 8);
    sum += __shfl_xor(sum, 16);
    sum += __shfl_xor(sum, 32);
    const float inv = 1.0f / sum;

    float acc[8] = {0.f, 0.f, 0.f, 0.f, 0.f, 0.f, 0.f, 0.f};
    #pragma unroll
    for (int g = 0; g < 4; ++g) {
        const float ag = e[g] * inv;
        #pragma unroll
        for (int j = 0; j < 8; ++j)
            acc[j] = fmaf(ag, (float)v8s[g][j], acc[j]);
    }
    #pragma unroll
    for (int j = 0; j < 8; ++j) {
        acc[j] += __shfl_xor(acc[j], 8);
        acc[j] += __shfl_xor(acc[j], 16);
        acc[j] += __shfl_xor(acc[j], 32);
    }
    if (wq == 0) {
        bf16x8 o;
        #pragma unroll
        for (int j = 0; j < 8; ++j) o[j] = (bf16_t)acc[j];
        *(bf16x8*)((char*)attn_out + row * 1024 + h * 128 + d8 * 16) = o;
    }
}

extern "C" void kernel_launch(void* const* d_in, const int* in_sizes, int n_in,
                              void* d_out, int out_size, void* d_ws, size_t ws_size,
                              hipStream_t stream) {
    (void)in_sizes; (void)n_in; (void)out_size; (void)ws_size;
    const int* nidx = (const int*)d_in[5];
    const int M = Bc * Sc;                        // 8192
    float* out = (float*)d_out;                   // fp32 output (round-7 finding)

    char* w = (char*)d_ws;
    bf16_t* xc   = (bf16_t*)(w + 256);            // 8 MB
    bf16_t* Wqc  = xc  + 4194304;                 // 0.5 MB each
    bf16_t* Wkc  = Wqc + 262144;
    bf16_t* Wvc  = Wkc + 262144;
    bf16_t* Woc  = Wvc + 262144;
    bf16_t* qkv  = Woc + 262144;                  // 24 MB
    bf16_t* attnS = xc;                           // reuse x-buffer after GEMM1

    convert_all<<<5120, 256, 0, stream>>>(
        (const float*)d_in[0], (const float*)d_in[1], (const float*)d_in[2],
        (const float*)d_in[3], (const float*)d_in[4],
        xc, Wqc, Wkc, Wvc, Woc);

    // Fused QKV projection: M=8192, N=1536, K=512 (bf16 out), 8-phase 256^2.
    gemm8p<<<dim3(32, 6), 512, 0, stream>>>(xc, Wqc, Wkc, Wvc, qkv);

    // Neighbor attention (register-only, 1 query/wave, max TLP).
    attn_fast<<<(Bc * Hc * Sc) / 4, 256, 0, stream>>>(qkv, nidx, attnS);

    // Output projection: M=8192, N=512, K=512 -> fp32 d_out.
    gemm_bt<128, 64, 4, 2, true><<<dim3(M / 128, 512 / 64), 256, 0, stream>>>(
        attnS, 512, Woc, Woc, Woc, 512, 0, out, Dc, Dc);
}